// Round 10
// baseline (117.010 us; speedup 1.0000x reference)
//
#include <hip/hip_runtime.h>

// inputs (256,128,64) f32, mask (256,128) i32, qparams (4,2,10) f32,
// W (4,256,10) f32, b (4,256) f32.
// out f32: outputs(256,128,256) ++ hx(128,256) ++ cx(128,256).
#define T_LEN 256
#define BATCH 128
#define NQ 10
#define HID 256
#define OUT_HX (T_LEN * BATCH * HID)
#define OUT_CX (OUT_HX + BATCH * HID)

#define KS  (-1.44269504089f)   // -log2(e): sigmoid scale
#define KT2 (-2.88539008178f)   // -2*log2(e): tanh scale

// ---------------- K1: circuit z precompute ----------------
// One thread per (t,g). Math identical to the validated analytic DP.
// Gate exp2-scale folded into z (sigmoid gates *KS, tanh gate *KT2).
// Layout zws[b][t][40] (n-major, g in float4 lanes): per-t row is 160B
// contiguous -> scanker's wave-uniform row loads are scalar (SMEM) hits.
__global__ __launch_bounds__(256) void zker(
    const float* __restrict__ inputs,
    const float* __restrict__ qparams,
    float* __restrict__ zws)
{
  const int b   = blockIdx.x;
  const int tq  = blockIdx.y;
  const int tid = threadIdx.x;
  const int t   = tq * 64 + (tid >> 2);
  const int g   = tid & 3;

  const float sg = (g == 2) ? KT2 : KS;

  float th0[NQ], cth[NQ], sth[NQ];
#pragma unroll
  for (int k = 0; k < NQ; ++k) {
    th0[k]   = qparams[g * 2 * NQ + k];
    float t1 = qparams[g * 2 * NQ + NQ + k];
    sth[k] = __sinf(t1);
    cth[k] = __cosf(t1);
  }
  float cphi[NQ], sphi[NQ];
  const float* xp = inputs + (t * BATCH + b) * 64;
#pragma unroll
  for (int k = 0; k < NQ; ++k) {
    float ang = xp[k] + th0[k];
    sphi[k] = __sinf(ang);
    cphi[k] = __cosf(ang);
  }
  float* zout = zws + (b * T_LEN + t) * 40 + g;   // + n*4 per qubit
#pragma unroll
  for (int w = 0; w < NQ; ++w) {
    float vI, vZ, vY, vX; int js;
    if (w == NQ - 1) { vI = 0.f; vZ = cth[NQ-1]; vY = sth[NQ-1]; vX = 0.f; js = NQ - 2; }
    else             { vI = 1.f; vZ = 0.f; vY = 0.f; vX = 0.f; js = w; }
#pragma unroll
    for (int j = js; j >= 0; --j) {
      float nI = cth[j] * (cphi[j+1] * vZ - sphi[j+1] * vY);
      float nZ = cth[j] * vI;
      float nY = sth[j] * vX;
      float nX = -sth[j] * (sphi[j+1] * vZ + cphi[j+1] * vY);
      vI = nI; vZ = nZ; vY = nY; vX = nX;
    }
    zout[w * 4] = (vI + cphi[0] * vZ - sphi[0] * vY) * sg;
  }
}

// ---------------- K2: lane = h, chunked scan, no recompute ----------------
// R8 counters (VALUBusy 63.5%, 27us VALU-busy) match the arithmetic model:
// VALU-throughput-bound on the gate GEMM (17us chip-wide floor) x1.75
// recompute. This version stores each chunk's a[32], w[32] in registers in
// pass 1 (f/i/g dots computed ONCE); pass 2 recomputes only the o-gate
// (10 scalar .w loads + 10 FMA) and runs the pure recurrence. Per-t cost:
// 40 FMA (minimal) + 10 trans, was 70 + 16. VGPR ~125 -> still 16 waves/CU.
__global__ __launch_bounds__(512, 4) void scanker(
    const float* __restrict__ zws,
    const int*  __restrict__ mask,
    const float* __restrict__ W,
    const float* __restrict__ bias,
    float* __restrict__ out)
{
  const int b    = blockIdx.x;      // 0..127
  const int h0   = blockIdx.y * 64; // h-group base (4 groups)
  const int tid  = threadIdx.x;     // 0..511
  const int lane = tid & 63;
  const int wavu = __builtin_amdgcn_readfirstlane(tid >> 6);  // t-chunk id
  const int h    = h0 + lane;

  __shared__ float mk[T_LEN];       // 1024 B
  __shared__ float cA[8][64];       // 2048 B  chunk composite A
  __shared__ float cW[8][64];       // 2048 B  chunk composite W

  for (int t = tid; t < T_LEN; t += 512) mk[t] = (float)mask[t * BATCH + b];

  // per-lane weights: loaded once into VGPRs
  float Wf[NQ], Wi[NQ], Wg[NQ], Wo[NQ];
#pragma unroll
  for (int n = 0; n < NQ; ++n) {
    Wf[n] = W[(0 * HID + h) * NQ + n];
    Wi[n] = W[(1 * HID + h) * NQ + n];
    Wg[n] = W[(2 * HID + h) * NQ + n];
    Wo[n] = W[(3 * HID + h) * NQ + n];
  }
  const float bf = bias[0 * HID + h] * KS;
  const float bi = bias[1 * HID + h] * KS;
  const float bg = bias[2 * HID + h] * KT2;
  const float bo = bias[3 * HID + h] * KS;

  const float* zb = zws + b * T_LEN * 40;
  __syncthreads();   // mk ready

  // ---- pass 1: f/i/g gates ONCE; keep per-step (a, w) in registers ----
  float av[32], wv[32];
  float A = 1.f, Wc = 0.f;
#pragma unroll
  for (int k = 0; k < 32; ++k) {
    const int t = wavu * 32 + k;                    // wave-uniform
    const float* zr = zb + t * 40;                  // uniform row -> s_load
    const float m = mk[t];
    const float onem = 1.f - m;
    float p0 = bf, p1 = bi, p2 = bg;
#pragma unroll
    for (int n = 0; n < NQ; ++n) {
      p0 = fmaf(zr[n * 4 + 0], Wf[n], p0);
      p1 = fmaf(zr[n * 4 + 1], Wi[n], p1);
      p2 = fmaf(zr[n * 4 + 2], Wg[n], p2);
    }
    const float uf = __builtin_amdgcn_rcpf(1.f + __builtin_amdgcn_exp2f(p0));
    const float ui = __builtin_amdgcn_rcpf(1.f + __builtin_amdgcn_exp2f(p1));
    const float ug = __builtin_amdgcn_rcpf(1.f + __builtin_amdgcn_exp2f(p2));
    const float a  = fmaf(m, uf, onem);             // decay a_t
    const float wt = m * ui * fmaf(2.f, ug, -1.f);  // input w_t (m*m==m)
    av[k] = a;
    wv[k] = wt;
    Wc = fmaf(a, Wc, wt);
    A  = a * A;
  }
  cA[wavu][lane] = A;
  cW[wavu][lane] = Wc;
  __syncthreads();

  // ---- carry-in for this chunk: compose preceding segments ----
  float c = 0.f;
  for (int k = 0; k < wavu; ++k)                    // wave-uniform trip count
    c = fmaf(cA[k][lane], c, cW[k][lane]);

  // ---- pass 2: o-gate only + pure recurrence + store ----
  float hv = 0.f;
#pragma unroll
  for (int k = 0; k < 32; ++k) {
    const int t = wavu * 32 + k;
    const float* zr = zb + t * 40;
    const float m = mk[t];
    float p3 = bo;
#pragma unroll
    for (int n = 0; n < NQ; ++n)
      p3 = fmaf(zr[n * 4 + 3], Wo[n], p3);          // .w lane of z row
    const float uo = __builtin_amdgcn_rcpf(1.f + __builtin_amdgcn_exp2f(p3));
    const float om = fmaf(m, uo, 1.f - m);
    c = fmaf(av[k], c, wv[k]);
    const float ec = __builtin_amdgcn_exp2f(c * KT2);
    const float tc = fmaf(2.f, __builtin_amdgcn_rcpf(1.f + ec), -1.f);
    hv = om * tc;
    out[t * (BATCH * HID) + b * HID + h] = hv;      // 256B coalesced per t
  }
  if (wavu == 7) {
    out[OUT_HX + b * HID + h] = hv;
    out[OUT_CX + b * HID + h] = c;
  }
}

extern "C" void kernel_launch(void* const* d_in, const int* in_sizes, int n_in,
                              void* d_out, int out_size, void* d_ws, size_t ws_size,
                              hipStream_t stream)
{
  // identify arrays by unique element counts (order-proof)
  int ii = 0, im = 1, iq = 2, iw = 3, ib = 4;
  for (int i = 0; i < n_in; ++i) {
    switch (in_sizes[i]) {
      case 2097152: ii = i; break;   // inputs (256,128,64)
      case 32768:   im = i; break;   // mask (256,128)
      case 80:      iq = i; break;   // qparams (4,2,10)
      case 10240:   iw = i; break;   // W (4,256,10)
      case 1024:    ib = i; break;   // b (4,256)
      default: break;
    }
  }
  const float* inputs  = (const float*)d_in[ii];
  const int*   mask    = (const int*)d_in[im];
  const float* qparams = (const float*)d_in[iq];
  const float* W       = (const float*)d_in[iw];
  const float* bias    = (const float*)d_in[ib];
  float*       out     = (float*)d_out;
  float*       zws     = (float*)d_ws;   // needs 128*256*40*4 = 5.25 MB

  zker<<<dim3(BATCH, 4), dim3(256), 0, stream>>>(inputs, qparams, zws);
  scanker<<<dim3(BATCH, 4), dim3(512), 0, stream>>>(zws, mask, W, bias, out);
}

// Round 11
// 116.597 us; speedup vs baseline: 1.0035x; 1.0035x over previous
//
#include <hip/hip_runtime.h>

// inputs (256,128,64) f32, mask (256,128) i32, qparams (4,2,10) f32,
// W (4,256,10) f32, b (4,256) f32.
// out f32: outputs(256,128,256) ++ hx(128,256) ++ cx(128,256).
#define T_LEN 256
#define BATCH 128
#define NQ 10
#define HID 256
#define OUT_HX (T_LEN * BATCH * HID)
#define OUT_CX (OUT_HX + BATCH * HID)

#define KS  (-1.44269504089f)   // -log2(e): sigmoid scale
#define KT2 (-2.88539008178f)   // -2*log2(e): tanh scale

// ---------------- K1: circuit z precompute ----------------
// One thread per (t,g). Math identical to the validated analytic DP.
// Gate exp2-scale folded into z (sigmoid gates *KS, tanh gate *KT2).
// Layout zws[b][t][40] (n-major, g in float4 lanes): per-t row is 160B
// contiguous -> scanker's wave-uniform row loads are scalar (SMEM) hits.
__global__ __launch_bounds__(256) void zker(
    const float* __restrict__ inputs,
    const float* __restrict__ qparams,
    float* __restrict__ zws)
{
  const int b   = blockIdx.x;
  const int tq  = blockIdx.y;
  const int tid = threadIdx.x;
  const int t   = tq * 64 + (tid >> 2);
  const int g   = tid & 3;

  const float sg = (g == 2) ? KT2 : KS;

  float th0[NQ], cth[NQ], sth[NQ];
#pragma unroll
  for (int k = 0; k < NQ; ++k) {
    th0[k]   = qparams[g * 2 * NQ + k];
    float t1 = qparams[g * 2 * NQ + NQ + k];
    sth[k] = __sinf(t1);
    cth[k] = __cosf(t1);
  }
  float cphi[NQ], sphi[NQ];
  const float* xp = inputs + (t * BATCH + b) * 64;
#pragma unroll
  for (int k = 0; k < NQ; ++k) {
    float ang = xp[k] + th0[k];
    sphi[k] = __sinf(ang);
    cphi[k] = __cosf(ang);
  }
  float* zout = zws + (b * T_LEN + t) * 40 + g;   // + n*4 per qubit
#pragma unroll
  for (int w = 0; w < NQ; ++w) {
    float vI, vZ, vY, vX; int js;
    if (w == NQ - 1) { vI = 0.f; vZ = cth[NQ-1]; vY = sth[NQ-1]; vX = 0.f; js = NQ - 2; }
    else             { vI = 1.f; vZ = 0.f; vY = 0.f; vX = 0.f; js = w; }
#pragma unroll
    for (int j = js; j >= 0; --j) {
      float nI = cth[j] * (cphi[j+1] * vZ - sphi[j+1] * vY);
      float nZ = cth[j] * vI;
      float nY = sth[j] * vX;
      float nX = -sth[j] * (sphi[j+1] * vZ + cphi[j+1] * vY);
      vI = nI; vZ = nZ; vY = nY; vX = nX;
    }
    zout[w * 4] = (vI + cphi[0] * vZ - sphi[0] * vY) * sg;
  }
}

// ---------------- K2: lane = h chunked scan, mask-skip, wv-banked ----------------
// R8/R10 post-mortem: VGPR_Count 36/60 proves the 40 per-lane weights (and
// R10's banked arrays) were SPILLED to scratch - the allocator's occupancy
// heuristic under-allocated (grid caps occupancy at 16 waves/CU regardless).
// Fixes: (1) __launch_bounds__(512,2) -> 256-reg budget, weights resident;
// (2) bank only wv[32], recompute f-dot & o-dot in pass 2 (~95 VGPR, safe
// margin to the 128 cliff); (3) wave-uniform mask skip: lane=h makes
// m=mask[t*B+b] uniform and exactly {0,1}; m==0 is an exact identity step
// (a=1,w=0,om=1,hv=tanh(c)=cached tc) -> scalar branch skips the entire
// gate body in both passes, bit-identical to the multiply form (~50% of t).
__global__ __launch_bounds__(512, 2) void scanker(
    const float* __restrict__ zws,
    const int*  __restrict__ mask,
    const float* __restrict__ W,
    const float* __restrict__ bias,
    float* __restrict__ out)
{
  const int b    = blockIdx.x;      // 0..127
  const int h0   = blockIdx.y * 64; // h-group base (4 groups)
  const int tid  = threadIdx.x;     // 0..511
  const int lane = tid & 63;
  const int wavu = __builtin_amdgcn_readfirstlane(tid >> 6);  // t-chunk id
  const int h    = h0 + lane;

  __shared__ float cA[8][64];       // 2048 B  chunk composite A
  __shared__ float cW[8][64];       // 2048 B  chunk composite W

  // per-lane weights: loaded once into VGPRs (40 regs - must stay resident)
  float Wf[NQ], Wi[NQ], Wg[NQ], Wo[NQ];
#pragma unroll
  for (int n = 0; n < NQ; ++n) {
    Wf[n] = W[(0 * HID + h) * NQ + n];
    Wi[n] = W[(1 * HID + h) * NQ + n];
    Wg[n] = W[(2 * HID + h) * NQ + n];
    Wo[n] = W[(3 * HID + h) * NQ + n];
  }
  const float bf = bias[0 * HID + h] * KS;
  const float bi = bias[1 * HID + h] * KS;
  const float bg = bias[2 * HID + h] * KT2;
  const float bo = bias[3 * HID + h] * KS;

  const float* zb = zws + b * T_LEN * 40;

  // ---- pass 1: compose chunk (A, Wc); bank w_t; skip masked t ----
  float wv[32];
  float A = 1.f, Wc = 0.f;
#pragma unroll
  for (int k = 0; k < 32; ++k) {
    const int t = wavu * 32 + k;                    // wave-uniform
    if (mask[t * BATCH + b]) {                      // uniform scalar branch
      const float4* zrow = (const float4*)(zb + t * 40);  // uniform -> s_load
      float p0 = bf, p1 = bi, p2 = bg;
#pragma unroll
      for (int n = 0; n < NQ; ++n) {
        const float4 z = zrow[n];
        p0 = fmaf(z.x, Wf[n], p0);
        p1 = fmaf(z.y, Wi[n], p1);
        p2 = fmaf(z.z, Wg[n], p2);
      }
      const float a  = __builtin_amdgcn_rcpf(1.f + __builtin_amdgcn_exp2f(p0));
      const float ui = __builtin_amdgcn_rcpf(1.f + __builtin_amdgcn_exp2f(p1));
      const float ug = __builtin_amdgcn_rcpf(1.f + __builtin_amdgcn_exp2f(p2));
      const float wt = ui * fmaf(2.f, ug, -1.f);    // m==1 exactly
      wv[k] = wt;
      Wc = fmaf(a, Wc, wt);
      A  = a * A;
    } else {
      wv[k] = 0.f;                                  // identity step
    }
  }
  cA[wavu][lane] = A;
  cW[wavu][lane] = Wc;
  __syncthreads();

  // ---- carry-in for this chunk: compose preceding segments ----
  float c = 0.f;
  for (int k = 0; k < wavu; ++k)                    // wave-uniform trip count
    c = fmaf(cA[k][lane], c, cW[k][lane]);

  // cached tanh(c): masked steps emit hv = tc directly (om == 1)
  float tc;
  {
    const float ec = __builtin_amdgcn_exp2f(c * KT2);
    tc = fmaf(2.f, __builtin_amdgcn_rcpf(1.f + ec), -1.f);
  }

  // ---- pass 2: recompute f/o dots (active t only) + recurrence + store ----
  float hv = tc;
#pragma unroll
  for (int k = 0; k < 32; ++k) {
    const int t = wavu * 32 + k;
    if (mask[t * BATCH + b]) {                      // K$-hot, uniform branch
      const float4* zrow = (const float4*)(zb + t * 40);
      float p0 = bf, p3 = bo;
#pragma unroll
      for (int n = 0; n < NQ; ++n) {
        const float4 z = zrow[n];
        p0 = fmaf(z.x, Wf[n], p0);                  // f gate -> a
        p3 = fmaf(z.w, Wo[n], p3);                  // o gate
      }
      const float a  = __builtin_amdgcn_rcpf(1.f + __builtin_amdgcn_exp2f(p0));
      const float uo = __builtin_amdgcn_rcpf(1.f + __builtin_amdgcn_exp2f(p3));
      c = fmaf(a, c, wv[k]);
      const float ec = __builtin_amdgcn_exp2f(c * KT2);
      tc = fmaf(2.f, __builtin_amdgcn_rcpf(1.f + ec), -1.f);
      hv = uo * tc;
    } else {
      hv = tc;                                      // om==1, c unchanged
    }
    out[t * (BATCH * HID) + b * HID + h] = hv;      // 256B coalesced per t
  }
  if (wavu == 7) {
    out[OUT_HX + b * HID + h] = hv;
    out[OUT_CX + b * HID + h] = c;
  }
}

extern "C" void kernel_launch(void* const* d_in, const int* in_sizes, int n_in,
                              void* d_out, int out_size, void* d_ws, size_t ws_size,
                              hipStream_t stream)
{
  // identify arrays by unique element counts (order-proof)
  int ii = 0, im = 1, iq = 2, iw = 3, ib = 4;
  for (int i = 0; i < n_in; ++i) {
    switch (in_sizes[i]) {
      case 2097152: ii = i; break;   // inputs (256,128,64)
      case 32768:   im = i; break;   // mask (256,128)
      case 80:      iq = i; break;   // qparams (4,2,10)
      case 10240:   iw = i; break;   // W (4,256,10)
      case 1024:    ib = i; break;   // b (4,256)
      default: break;
    }
  }
  const float* inputs  = (const float*)d_in[ii];
  const int*   mask    = (const int*)d_in[im];
  const float* qparams = (const float*)d_in[iq];
  const float* W       = (const float*)d_in[iw];
  const float* bias    = (const float*)d_in[ib];
  float*       out     = (float*)d_out;
  float*       zws     = (float*)d_ws;   // needs 128*256*40*4 = 5.25 MB

  zker<<<dim3(BATCH, 4), dim3(256), 0, stream>>>(inputs, qparams, zws);
  scanker<<<dim3(BATCH, 4), dim3(512), 0, stream>>>(zws, mask, W, bias, out);
}

// Round 12
// 101.330 us; speedup vs baseline: 1.1547x; 1.1507x over previous
//
#include <hip/hip_runtime.h>

// inputs (256,128,64) f32, mask (256,128) i32, qparams (4,2,10) f32,
// W (4,256,10) f32, b (4,256) f32.
// out f32: outputs(256,128,256) ++ hx(128,256) ++ cx(128,256).
#define T_LEN 256
#define BATCH 128
#define NQ 10
#define HID 256
#define OUT_HX (T_LEN * BATCH * HID)
#define OUT_CX (OUT_HX + BATCH * HID)

#define KS  (-1.44269504089f)   // -log2(e): sigmoid scale
#define KT2 (-2.88539008178f)   // -2*log2(e): tanh scale

// ---------------- K1: circuit z precompute ----------------
// One thread per (t,g). Math identical to the validated analytic DP.
// Gate exp2-scale folded into z (sigmoid gates *KS, tanh gate *KT2).
// Layout zws[b][t][40] (n-major, g in float4 lanes). Masked t skipped
// entirely (their rows are never read by scanker).
__global__ __launch_bounds__(256) void zker(
    const float* __restrict__ inputs,
    const int*  __restrict__ mask,
    const float* __restrict__ qparams,
    float* __restrict__ zws)
{
  const int b   = blockIdx.x;
  const int tq  = blockIdx.y;
  const int tid = threadIdx.x;
  const int t   = tq * 64 + (tid >> 2);
  const int g   = tid & 3;

  if (mask[t * BATCH + b] == 0) return;   // row never read downstream

  const float sg = (g == 2) ? KT2 : KS;

  float th0[NQ], cth[NQ], sth[NQ];
#pragma unroll
  for (int k = 0; k < NQ; ++k) {
    th0[k]   = qparams[g * 2 * NQ + k];
    float t1 = qparams[g * 2 * NQ + NQ + k];
    sth[k] = __sinf(t1);
    cth[k] = __cosf(t1);
  }
  float cphi[NQ], sphi[NQ];
  const float* xp = inputs + (t * BATCH + b) * 64;
#pragma unroll
  for (int k = 0; k < NQ; ++k) {
    float ang = xp[k] + th0[k];
    sphi[k] = __sinf(ang);
    cphi[k] = __cosf(ang);
  }
  float* zout = zws + (b * T_LEN + t) * 40 + g;   // + n*4 per qubit
#pragma unroll
  for (int w = 0; w < NQ; ++w) {
    float vI, vZ, vY, vX; int js;
    if (w == NQ - 1) { vI = 0.f; vZ = cth[NQ-1]; vY = sth[NQ-1]; vX = 0.f; js = NQ - 2; }
    else             { vI = 1.f; vZ = 0.f; vY = 0.f; vX = 0.f; js = w; }
#pragma unroll
    for (int j = js; j >= 0; --j) {
      float nI = cth[j] * (cphi[j+1] * vZ - sphi[j+1] * vY);
      float nZ = cth[j] * vI;
      float nY = sth[j] * vX;
      float nX = -sth[j] * (sphi[j+1] * vZ + cphi[j+1] * vY);
      vI = nI; vZ = nZ; vY = nY; vX = nX;
    }
    zout[w * 4] = (vI + cphi[0] * vZ - sphi[0] * vY) * sg;
  }
}

// ---------------- K2: lane = h chunked scan, LDS-z, bitmask-skip ----------------
// R8-R11 post-mortem: the ~45us plateau = serial per-row memory waits
// (z s_loads ~300cy, mask s_load+branch, banked-array scratch round-trips),
// with only 4 waves/SIMD to hide them. This version removes all three:
// z staged to LDS once (coalesced), rows re-read as uniform-address
// ds_read_b128 (broadcast, ~60cy, batchable); mask collapsed to a per-chunk
// 32-bit SGPR bitmask via one __ballot (per-row test = s_and, zero memory);
// NO banked arrays (pass 2 recomputes gates from LDS - cheap now, and no
// scratch). Exact-identity skip for m==0 rows is bit-identical to the
// multiply form since m ∈ {0,1} exactly.
__global__ __launch_bounds__(512, 4) void scanker(
    const float* __restrict__ zws,
    const int*  __restrict__ mask,
    const float* __restrict__ W,
    const float* __restrict__ bias,
    float* __restrict__ out)
{
  const int b    = blockIdx.x;      // 0..127
  const int h0   = blockIdx.y * 64; // h-group base (4 groups)
  const int tid  = threadIdx.x;     // 0..511
  const int lane = tid & 63;
  const int wavu = __builtin_amdgcn_readfirstlane(tid >> 6);  // t-chunk id
  const int h    = h0 + lane;

  __shared__ float4 zl4[T_LEN * 10];   // 40960 B, [t][10] float4 rows
  __shared__ unsigned int mbits[8];    // 32 B, per-chunk mask bits
  __shared__ float cA[8][64];          // 2048 B  chunk composite A
  __shared__ float cW[8][64];          // 2048 B  chunk composite W

  // stage z[b] (40KB): coalesced global float4 -> linear LDS
  {
    const float4* zg = (const float4*)(zws + b * T_LEN * 40);
    for (int i = tid; i < T_LEN * 10; i += 512) zl4[i] = zg[i];
  }
  // mask -> bitmask: wave w (w<4) ballots t = w*64+lane; low/high 32 bits
  // are chunks 2w / 2w+1 (chunk c covers t = c*32 + k, bit k)
  if (tid < 256) {
    const int mv = mask[tid * BATCH + b];
    const unsigned long long bal = __ballot(mv != 0);
    if ((tid & 63) == 0) {
      mbits[(tid >> 6) * 2]     = (unsigned int)bal;
      mbits[(tid >> 6) * 2 + 1] = (unsigned int)(bal >> 32);
    }
  }

  // per-lane weights: 40 VGPRs, loaded once (verified resident in R11)
  float Wf[NQ], Wi[NQ], Wg[NQ], Wo[NQ];
#pragma unroll
  for (int n = 0; n < NQ; ++n) {
    Wf[n] = W[(0 * HID + h) * NQ + n];
    Wi[n] = W[(1 * HID + h) * NQ + n];
    Wg[n] = W[(2 * HID + h) * NQ + n];
    Wo[n] = W[(3 * HID + h) * NQ + n];
  }
  const float bf = bias[0 * HID + h] * KS;
  const float bi = bias[1 * HID + h] * KS;
  const float bg = bias[2 * HID + h] * KT2;
  const float bo = bias[3 * HID + h] * KS;

  __syncthreads();

  const unsigned int mb =
      __builtin_amdgcn_readfirstlane(mbits[wavu]);   // SGPR chunk mask

  // ---- pass 1: compose chunk affine op (A, Wc); skip masked rows ----
  float A = 1.f, Wc = 0.f;
  {
    unsigned int mrem = mb;
    for (int k = 0; k < 32; ++k, mrem >>= 1) {
      if (mrem & 1u) {                               // uniform scalar branch
        const int zt = (wavu * 32 + k) * 10;
        float p0 = bf, p1 = bi, p2 = bg;
#pragma unroll
        for (int n = 0; n < NQ; ++n) {
          const float4 z = zl4[zt + n];              // uniform ds_read_b128
          p0 = fmaf(z.x, Wf[n], p0);
          p1 = fmaf(z.y, Wi[n], p1);
          p2 = fmaf(z.z, Wg[n], p2);
        }
        const float a  = __builtin_amdgcn_rcpf(1.f + __builtin_amdgcn_exp2f(p0));
        const float ui = __builtin_amdgcn_rcpf(1.f + __builtin_amdgcn_exp2f(p1));
        const float ug = __builtin_amdgcn_rcpf(1.f + __builtin_amdgcn_exp2f(p2));
        const float wt = ui * fmaf(2.f, ug, -1.f);   // m==1 exactly
        Wc = fmaf(a, Wc, wt);
        A  = a * A;
      }
    }
  }
  cA[wavu][lane] = A;
  cW[wavu][lane] = Wc;
  __syncthreads();

  // ---- carry-in for this chunk: compose preceding segments ----
  float c = 0.f;
  for (int k = 0; k < wavu; ++k)                     // wave-uniform trips
    c = fmaf(cA[k][lane], c, cW[k][lane]);

  // cached tanh(c): masked steps emit hv = tc directly (om == 1)
  float tc;
  {
    const float ec = __builtin_amdgcn_exp2f(c * KT2);
    tc = fmaf(2.f, __builtin_amdgcn_rcpf(1.f + ec), -1.f);
  }

  // ---- pass 2: recompute gates from LDS + recurrence + store ----
  float hv = tc;
  {
    unsigned int mrem = mb;
    for (int k = 0; k < 32; ++k, mrem >>= 1) {
      const int t = wavu * 32 + k;
      if (mrem & 1u) {
        const int zt = t * 10;
        float p0 = bf, p1 = bi, p2 = bg, p3 = bo;
#pragma unroll
        for (int n = 0; n < NQ; ++n) {
          const float4 z = zl4[zt + n];
          p0 = fmaf(z.x, Wf[n], p0);
          p1 = fmaf(z.y, Wi[n], p1);
          p2 = fmaf(z.z, Wg[n], p2);
          p3 = fmaf(z.w, Wo[n], p3);
        }
        const float a  = __builtin_amdgcn_rcpf(1.f + __builtin_amdgcn_exp2f(p0));
        const float ui = __builtin_amdgcn_rcpf(1.f + __builtin_amdgcn_exp2f(p1));
        const float ug = __builtin_amdgcn_rcpf(1.f + __builtin_amdgcn_exp2f(p2));
        const float uo = __builtin_amdgcn_rcpf(1.f + __builtin_amdgcn_exp2f(p3));
        c = fmaf(a, c, ui * fmaf(2.f, ug, -1.f));
        const float ec = __builtin_amdgcn_exp2f(c * KT2);
        tc = fmaf(2.f, __builtin_amdgcn_rcpf(1.f + ec), -1.f);
        hv = uo * tc;
      } else {
        hv = tc;                                     // om==1, c unchanged
      }
      out[t * (BATCH * HID) + b * HID + h] = hv;     // 256B coalesced per t
    }
  }
  if (wavu == 7) {
    out[OUT_HX + b * HID + h] = hv;
    out[OUT_CX + b * HID + h] = c;
  }
}

extern "C" void kernel_launch(void* const* d_in, const int* in_sizes, int n_in,
                              void* d_out, int out_size, void* d_ws, size_t ws_size,
                              hipStream_t stream)
{
  // identify arrays by unique element counts (order-proof)
  int ii = 0, im = 1, iq = 2, iw = 3, ib = 4;
  for (int i = 0; i < n_in; ++i) {
    switch (in_sizes[i]) {
      case 2097152: ii = i; break;   // inputs (256,128,64)
      case 32768:   im = i; break;   // mask (256,128)
      case 80:      iq = i; break;   // qparams (4,2,10)
      case 10240:   iw = i; break;   // W (4,256,10)
      case 1024:    ib = i; break;   // b (4,256)
      default: break;
    }
  }
  const float* inputs  = (const float*)d_in[ii];
  const int*   mask    = (const int*)d_in[im];
  const float* qparams = (const float*)d_in[iq];
  const float* W       = (const float*)d_in[iw];
  const float* bias    = (const float*)d_in[ib];
  float*       out     = (float*)d_out;
  float*       zws     = (float*)d_ws;   // needs 128*256*40*4 = 5.25 MB

  zker<<<dim3(BATCH, 4), dim3(256), 0, stream>>>(inputs, mask, qparams, zws);
  scanker<<<dim3(BATCH, 4), dim3(512), 0, stream>>>(zws, mask, W, bias, out);
}

// Round 13
// 101.007 us; speedup vs baseline: 1.1584x; 1.0032x over previous
//
#include <hip/hip_runtime.h>

// inputs (256,128,64) f32, mask (256,128) i32, qparams (4,2,10) f32,
// W (4,256,10) f32, b (4,256) f32.
// out f32: outputs(256,128,256) ++ hx(128,256) ++ cx(128,256).
#define T_LEN 256
#define BATCH 128
#define NQ 10
#define HID 256
#define OUT_HX (T_LEN * BATCH * HID)
#define OUT_CX (OUT_HX + BATCH * HID)

#define KS  (-1.44269504089f)   // -log2(e): sigmoid scale
#define KT2 (-2.88539008178f)   // -2*log2(e): tanh scale

// ---------------- K1: circuit z precompute ----------------
// One thread per (t,g). Math identical to the validated analytic DP.
// Gate exp2-scale folded into z (sigmoid gates *KS, tanh gate *KT2).
// Layout zws[b][t][40] (n-major, g in float4 lanes). Masked t skipped
// entirely (their rows are never read by scanker).
__global__ __launch_bounds__(256) void zker(
    const float* __restrict__ inputs,
    const int*  __restrict__ mask,
    const float* __restrict__ qparams,
    float* __restrict__ zws)
{
  const int b   = blockIdx.x;
  const int tq  = blockIdx.y;
  const int tid = threadIdx.x;
  const int t   = tq * 64 + (tid >> 2);
  const int g   = tid & 3;

  if (mask[t * BATCH + b] == 0) return;   // row never read downstream

  const float sg = (g == 2) ? KT2 : KS;

  float th0[NQ], cth[NQ], sth[NQ];
#pragma unroll
  for (int k = 0; k < NQ; ++k) {
    th0[k]   = qparams[g * 2 * NQ + k];
    float t1 = qparams[g * 2 * NQ + NQ + k];
    sth[k] = __sinf(t1);
    cth[k] = __cosf(t1);
  }
  float cphi[NQ], sphi[NQ];
  const float* xp = inputs + (t * BATCH + b) * 64;
#pragma unroll
  for (int k = 0; k < NQ; ++k) {
    float ang = xp[k] + th0[k];
    sphi[k] = __sinf(ang);
    cphi[k] = __cosf(ang);
  }
  float* zout = zws + (b * T_LEN + t) * 40 + g;   // + n*4 per qubit
#pragma unroll
  for (int w = 0; w < NQ; ++w) {
    float vI, vZ, vY, vX; int js;
    if (w == NQ - 1) { vI = 0.f; vZ = cth[NQ-1]; vY = sth[NQ-1]; vX = 0.f; js = NQ - 2; }
    else             { vI = 1.f; vZ = 0.f; vY = 0.f; vX = 0.f; js = w; }
#pragma unroll
    for (int j = js; j >= 0; --j) {
      float nI = cth[j] * (cphi[j+1] * vZ - sphi[j+1] * vY);
      float nZ = cth[j] * vI;
      float nY = sth[j] * vX;
      float nX = -sth[j] * (sphi[j+1] * vZ + cphi[j+1] * vY);
      vI = nI; vZ = nZ; vY = nY; vX = nX;
    }
    zout[w * 4] = (vI + cphi[0] * vZ - sphi[0] * vY) * sg;
  }
}

// ---------------- K2: lane = h chunked scan, LDS-z, bitmask, UNROLLED ----------------
// R12 got 48->~33us via LDS-z + SGPR bitmask + no banked arrays. Remaining
// 2.5x gap vs issue-rate model: both pass loops were ROLLED - each row-visit
// exposes its full ds_read latency + 40cy dot chain serially (~130cy/row)
// with only 4 waves/SIMD to hide it. This version fully unrolls both passes
// with compile-time bit tests (mb & (1u<<k)): the scheduler can hoist row
// k+1's independent ds_reads/dots into row k's stall shadow. Same math
// bit-for-bit; no runtime-indexed register arrays (rule #20 safe).
__global__ __launch_bounds__(512, 4) void scanker(
    const float* __restrict__ zws,
    const int*  __restrict__ mask,
    const float* __restrict__ W,
    const float* __restrict__ bias,
    float* __restrict__ out)
{
  const int b    = blockIdx.x;      // 0..127
  const int h0   = blockIdx.y * 64; // h-group base (4 groups)
  const int tid  = threadIdx.x;     // 0..511
  const int lane = tid & 63;
  const int wavu = __builtin_amdgcn_readfirstlane(tid >> 6);  // t-chunk id
  const int h    = h0 + lane;

  __shared__ float4 zl4[T_LEN * 10];   // 40960 B, [t][10] float4 rows
  __shared__ unsigned int mbits[8];    // 32 B, per-chunk mask bits
  __shared__ float cA[8][64];          // 2048 B  chunk composite A
  __shared__ float cW[8][64];          // 2048 B  chunk composite W

  // stage z[b] (40KB): coalesced global float4 -> linear LDS
  {
    const float4* zg = (const float4*)(zws + b * T_LEN * 40);
    for (int i = tid; i < T_LEN * 10; i += 512) zl4[i] = zg[i];
  }
  // mask -> bitmask: wave w (w<4) ballots t = w*64+lane; low/high 32 bits
  // are chunks 2w / 2w+1 (chunk c covers t = c*32 + k, bit k)
  if (tid < 256) {
    const int mv = mask[tid * BATCH + b];
    const unsigned long long bal = __ballot(mv != 0);
    if ((tid & 63) == 0) {
      mbits[(tid >> 6) * 2]     = (unsigned int)bal;
      mbits[(tid >> 6) * 2 + 1] = (unsigned int)(bal >> 32);
    }
  }

  // per-lane weights: 40 VGPRs, loaded once
  float Wf[NQ], Wi[NQ], Wg[NQ], Wo[NQ];
#pragma unroll
  for (int n = 0; n < NQ; ++n) {
    Wf[n] = W[(0 * HID + h) * NQ + n];
    Wi[n] = W[(1 * HID + h) * NQ + n];
    Wg[n] = W[(2 * HID + h) * NQ + n];
    Wo[n] = W[(3 * HID + h) * NQ + n];
  }
  const float bf = bias[0 * HID + h] * KS;
  const float bi = bias[1 * HID + h] * KS;
  const float bg = bias[2 * HID + h] * KT2;
  const float bo = bias[3 * HID + h] * KS;

  __syncthreads();

  const unsigned int mb =
      __builtin_amdgcn_readfirstlane(mbits[wavu]);   // SGPR chunk mask
  const int ztbase = wavu * 32 * 10;

  // ---- pass 1: compose chunk affine op (A, Wc); skip masked rows ----
  float A = 1.f, Wc = 0.f;
#pragma unroll
  for (int k = 0; k < 32; ++k) {
    if (mb & (1u << k)) {                            // scalar branch, imm bit
      const int zt = ztbase + k * 10;
      float p0 = bf, p1 = bi, p2 = bg;
#pragma unroll
      for (int n = 0; n < NQ; ++n) {
        const float4 z = zl4[zt + n];                // uniform ds_read_b128
        p0 = fmaf(z.x, Wf[n], p0);
        p1 = fmaf(z.y, Wi[n], p1);
        p2 = fmaf(z.z, Wg[n], p2);
      }
      const float a  = __builtin_amdgcn_rcpf(1.f + __builtin_amdgcn_exp2f(p0));
      const float ui = __builtin_amdgcn_rcpf(1.f + __builtin_amdgcn_exp2f(p1));
      const float ug = __builtin_amdgcn_rcpf(1.f + __builtin_amdgcn_exp2f(p2));
      const float wt = ui * fmaf(2.f, ug, -1.f);     // m==1 exactly
      Wc = fmaf(a, Wc, wt);
      A  = a * A;
    }
  }
  cA[wavu][lane] = A;
  cW[wavu][lane] = Wc;
  __syncthreads();

  // ---- carry-in for this chunk: compose preceding segments ----
  float c = 0.f;
  for (int k = 0; k < wavu; ++k)                     // wave-uniform trips
    c = fmaf(cA[k][lane], c, cW[k][lane]);

  // cached tanh(c): masked steps emit hv = tc directly (om == 1)
  float tc;
  {
    const float ec = __builtin_amdgcn_exp2f(c * KT2);
    tc = fmaf(2.f, __builtin_amdgcn_rcpf(1.f + ec), -1.f);
  }

  // ---- pass 2: recompute gates from LDS + recurrence + store ----
  float* op = out + (wavu * 32) * (BATCH * HID) + b * HID + h;
  float hv = tc;
#pragma unroll
  for (int k = 0; k < 32; ++k) {
    if (mb & (1u << k)) {
      const int zt = ztbase + k * 10;
      float p0 = bf, p1 = bi, p2 = bg, p3 = bo;
#pragma unroll
      for (int n = 0; n < NQ; ++n) {
        const float4 z = zl4[zt + n];
        p0 = fmaf(z.x, Wf[n], p0);
        p1 = fmaf(z.y, Wi[n], p1);
        p2 = fmaf(z.z, Wg[n], p2);
        p3 = fmaf(z.w, Wo[n], p3);
      }
      const float a  = __builtin_amdgcn_rcpf(1.f + __builtin_amdgcn_exp2f(p0));
      const float ui = __builtin_amdgcn_rcpf(1.f + __builtin_amdgcn_exp2f(p1));
      const float ug = __builtin_amdgcn_rcpf(1.f + __builtin_amdgcn_exp2f(p2));
      const float uo = __builtin_amdgcn_rcpf(1.f + __builtin_amdgcn_exp2f(p3));
      c = fmaf(a, c, ui * fmaf(2.f, ug, -1.f));
      const float ec = __builtin_amdgcn_exp2f(c * KT2);
      tc = fmaf(2.f, __builtin_amdgcn_rcpf(1.f + ec), -1.f);
      hv = uo * tc;
    } else {
      hv = tc;                                       // om==1, c unchanged
    }
    op[k * (BATCH * HID)] = hv;                      // 256B coalesced per t
  }
  if (wavu == 7) {
    out[OUT_HX + b * HID + h] = hv;
    out[OUT_CX + b * HID + h] = c;
  }
}

extern "C" void kernel_launch(void* const* d_in, const int* in_sizes, int n_in,
                              void* d_out, int out_size, void* d_ws, size_t ws_size,
                              hipStream_t stream)
{
  // identify arrays by unique element counts (order-proof)
  int ii = 0, im = 1, iq = 2, iw = 3, ib = 4;
  for (int i = 0; i < n_in; ++i) {
    switch (in_sizes[i]) {
      case 2097152: ii = i; break;   // inputs (256,128,64)
      case 32768:   im = i; break;   // mask (256,128)
      case 80:      iq = i; break;   // qparams (4,2,10)
      case 10240:   iw = i; break;   // W (4,256,10)
      case 1024:    ib = i; break;   // b (4,256)
      default: break;
    }
  }
  const float* inputs  = (const float*)d_in[ii];
  const int*   mask    = (const int*)d_in[im];
  const float* qparams = (const float*)d_in[iq];
  const float* W       = (const float*)d_in[iw];
  const float* bias    = (const float*)d_in[ib];
  float*       out     = (float*)d_out;
  float*       zws     = (float*)d_ws;   // needs 128*256*40*4 = 5.25 MB

  zker<<<dim3(BATCH, 4), dim3(256), 0, stream>>>(inputs, mask, qparams, zws);
  scanker<<<dim3(BATCH, 4), dim3(512), 0, stream>>>(zws, mask, W, bias, out);
}

// Round 14
// 98.039 us; speedup vs baseline: 1.1935x; 1.0303x over previous
//
#include <hip/hip_runtime.h>

// inputs (256,128,64) f32, mask (256,128) i32, qparams (4,2,10) f32,
// W (4,256,10) f32, b (4,256) f32.
// out f32: outputs(256,128,256) ++ hx(128,256) ++ cx(128,256).
#define T_LEN 256
#define BATCH 128
#define NQ 10
#define HID 256
#define OUT_HX (T_LEN * BATCH * HID)
#define OUT_CX (OUT_HX + BATCH * HID)

#define KS  (-1.44269504089f)   // -log2(e): sigmoid scale
#define KT2 (-2.88539008178f)   // -2*log2(e): tanh scale

// ---------------- K1: circuit z precompute ----------------
// One thread per (t,g). Math identical to the validated analytic DP.
// Gate exp2-scale folded into z (sigmoid gates *KS, tanh gate *KT2).
// Layout zws[b][t][40] (n-major, g in float4 lanes). Masked t skipped
// entirely (their rows are never read by scanker).
__global__ __launch_bounds__(256) void zker(
    const float* __restrict__ inputs,
    const int*  __restrict__ mask,
    const float* __restrict__ qparams,
    float* __restrict__ zws)
{
  const int b   = blockIdx.x;
  const int tq  = blockIdx.y;
  const int tid = threadIdx.x;
  const int t   = tq * 64 + (tid >> 2);
  const int g   = tid & 3;

  if (mask[t * BATCH + b] == 0) return;   // row never read downstream

  const float sg = (g == 2) ? KT2 : KS;

  float th0[NQ], cth[NQ], sth[NQ];
#pragma unroll
  for (int k = 0; k < NQ; ++k) {
    th0[k]   = qparams[g * 2 * NQ + k];
    float t1 = qparams[g * 2 * NQ + NQ + k];
    sth[k] = __sinf(t1);
    cth[k] = __cosf(t1);
  }
  float cphi[NQ], sphi[NQ];
  const float* xp = inputs + (t * BATCH + b) * 64;
#pragma unroll
  for (int k = 0; k < NQ; ++k) {
    float ang = xp[k] + th0[k];
    sphi[k] = __sinf(ang);
    cphi[k] = __cosf(ang);
  }
  float* zout = zws + (b * T_LEN + t) * 40 + g;   // + n*4 per qubit
#pragma unroll
  for (int w = 0; w < NQ; ++w) {
    float vI, vZ, vY, vX; int js;
    if (w == NQ - 1) { vI = 0.f; vZ = cth[NQ-1]; vY = sth[NQ-1]; vX = 0.f; js = NQ - 2; }
    else             { vI = 1.f; vZ = 0.f; vY = 0.f; vX = 0.f; js = w; }
#pragma unroll
    for (int j = js; j >= 0; --j) {
      float nI = cth[j] * (cphi[j+1] * vZ - sphi[j+1] * vY);
      float nZ = cth[j] * vI;
      float nY = sth[j] * vX;
      float nX = -sth[j] * (sphi[j+1] * vZ + cphi[j+1] * vY);
      vI = nI; vZ = nZ; vY = nY; vX = nX;
    }
    zout[w * 4] = (vI + cphi[0] * vZ - sphi[0] * vY) * sg;
  }
}

// ---------------- K2: SINGLE-PASS banked scan (DS reads halved) ----------------
// R12/R13 post-mortem: kernel is DS-throughput-bound on uniform-broadcast
// ds_read_b128 of z rows (~16cy each, per-CU pipe): 2 passes x 10 reads x
// ~16 active rows x 16 waves/CU ~= 34us = measured. This version reads each
// active z row ONCE: pass 1 computes all 4 gate dots and banks a/w/om in
// registers (96 VGPR, all indices compile-time in the unrolled loop - rule
// #20 safe; launch_bounds(512,2) gives the allocator 256 regs so the banks
// stay resident, unlike R10's 128-cap spill). Pass 2 is a pure in-register
// expansion: zero z reads. DS per CU halves (~17us floor).
__global__ __launch_bounds__(512, 2) void scanker(
    const float* __restrict__ zws,
    const int*  __restrict__ mask,
    const float* __restrict__ W,
    const float* __restrict__ bias,
    float* __restrict__ out)
{
  const int b    = blockIdx.x;      // 0..127
  const int h0   = blockIdx.y * 64; // h-group base (4 groups)
  const int tid  = threadIdx.x;     // 0..511
  const int lane = tid & 63;
  const int wavu = __builtin_amdgcn_readfirstlane(tid >> 6);  // t-chunk id
  const int h    = h0 + lane;

  __shared__ float4 zl4[T_LEN * 10];   // 40960 B, [t][10] float4 rows
  __shared__ unsigned int mbits[8];    // 32 B, per-chunk mask bits
  __shared__ float cA[8][64];          // 2048 B  chunk composite A
  __shared__ float cW[8][64];          // 2048 B  chunk composite W

  // stage z[b] (40KB): coalesced global float4 -> linear LDS
  {
    const float4* zg = (const float4*)(zws + b * T_LEN * 40);
    for (int i = tid; i < T_LEN * 10; i += 512) zl4[i] = zg[i];
  }
  // mask -> bitmask: wave w (w<4) ballots t = w*64+lane; low/high 32 bits
  // are chunks 2w / 2w+1 (chunk c covers t = c*32 + k, bit k)
  if (tid < 256) {
    const int mv = mask[tid * BATCH + b];
    const unsigned long long bal = __ballot(mv != 0);
    if ((tid & 63) == 0) {
      mbits[(tid >> 6) * 2]     = (unsigned int)bal;
      mbits[(tid >> 6) * 2 + 1] = (unsigned int)(bal >> 32);
    }
  }

  // per-lane weights: 40 VGPRs, loaded once
  float Wf[NQ], Wi[NQ], Wg[NQ], Wo[NQ];
#pragma unroll
  for (int n = 0; n < NQ; ++n) {
    Wf[n] = W[(0 * HID + h) * NQ + n];
    Wi[n] = W[(1 * HID + h) * NQ + n];
    Wg[n] = W[(2 * HID + h) * NQ + n];
    Wo[n] = W[(3 * HID + h) * NQ + n];
  }
  const float bf = bias[0 * HID + h] * KS;
  const float bi = bias[1 * HID + h] * KS;
  const float bg = bias[2 * HID + h] * KT2;
  const float bo = bias[3 * HID + h] * KS;

  __syncthreads();

  const unsigned int mb =
      __builtin_amdgcn_readfirstlane(mbits[wavu]);   // SGPR chunk mask
  const int ztbase = wavu * 32 * 10;

  // ---- single gate pass: all 4 dots per active row; bank a/w/om ----
  float av[32], wv[32], ov[32];
  float A = 1.f, Wc = 0.f;
#pragma unroll
  for (int k = 0; k < 32; ++k) {
    if (mb & (1u << k)) {                            // scalar branch, imm bit
      const int zt = ztbase + k * 10;
      float p0 = bf, p1 = bi, p2 = bg, p3 = bo;
#pragma unroll
      for (int n = 0; n < NQ; ++n) {
        const float4 z = zl4[zt + n];                // uniform ds_read_b128
        p0 = fmaf(z.x, Wf[n], p0);
        p1 = fmaf(z.y, Wi[n], p1);
        p2 = fmaf(z.z, Wg[n], p2);
        p3 = fmaf(z.w, Wo[n], p3);
      }
      const float a  = __builtin_amdgcn_rcpf(1.f + __builtin_amdgcn_exp2f(p0));
      const float ui = __builtin_amdgcn_rcpf(1.f + __builtin_amdgcn_exp2f(p1));
      const float ug = __builtin_amdgcn_rcpf(1.f + __builtin_amdgcn_exp2f(p2));
      const float uo = __builtin_amdgcn_rcpf(1.f + __builtin_amdgcn_exp2f(p3));
      const float wt = ui * fmaf(2.f, ug, -1.f);     // m==1 exactly
      av[k] = a; wv[k] = wt; ov[k] = uo;
      Wc = fmaf(a, Wc, wt);
      A  = a * A;
    } else {
      av[k] = 1.f; wv[k] = 0.f; ov[k] = 1.f;         // exact identity step
    }
  }
  cA[wavu][lane] = A;
  cW[wavu][lane] = Wc;
  __syncthreads();

  // ---- carry-in for this chunk: compose preceding segments ----
  float c = 0.f;
  for (int k = 0; k < wavu; ++k)                     // wave-uniform trips
    c = fmaf(cA[k][lane], c, cW[k][lane]);

  // cached tanh(c): masked steps emit hv = tc directly (om == 1)
  float tc;
  {
    const float ec = __builtin_amdgcn_exp2f(c * KT2);
    tc = fmaf(2.f, __builtin_amdgcn_rcpf(1.f + ec), -1.f);
  }

  // ---- expansion: pure in-register recurrence + store (no z reads) ----
  float* op = out + (wavu * 32) * (BATCH * HID) + b * HID + h;
  float hv = tc;
#pragma unroll
  for (int k = 0; k < 32; ++k) {
    if (mb & (1u << k)) {
      c = fmaf(av[k], c, wv[k]);
      const float ec = __builtin_amdgcn_exp2f(c * KT2);
      tc = fmaf(2.f, __builtin_amdgcn_rcpf(1.f + ec), -1.f);
      hv = ov[k] * tc;
    } else {
      hv = tc;                                       // om==1, c unchanged
    }
    op[k * (BATCH * HID)] = hv;                      // 256B coalesced per t
  }
  if (wavu == 7) {
    out[OUT_HX + b * HID + h] = hv;
    out[OUT_CX + b * HID + h] = c;
  }
}

extern "C" void kernel_launch(void* const* d_in, const int* in_sizes, int n_in,
                              void* d_out, int out_size, void* d_ws, size_t ws_size,
                              hipStream_t stream)
{
  // identify arrays by unique element counts (order-proof)
  int ii = 0, im = 1, iq = 2, iw = 3, ib = 4;
  for (int i = 0; i < n_in; ++i) {
    switch (in_sizes[i]) {
      case 2097152: ii = i; break;   // inputs (256,128,64)
      case 32768:   im = i; break;   // mask (256,128)
      case 80:      iq = i; break;   // qparams (4,2,10)
      case 10240:   iw = i; break;   // W (4,256,10)
      case 1024:    ib = i; break;   // b (4,256)
      default: break;
    }
  }
  const float* inputs  = (const float*)d_in[ii];
  const int*   mask    = (const int*)d_in[im];
  const float* qparams = (const float*)d_in[iq];
  const float* W       = (const float*)d_in[iw];
  const float* bias    = (const float*)d_in[ib];
  float*       out     = (float*)d_out;
  float*       zws     = (float*)d_ws;   // needs 128*256*40*4 = 5.25 MB

  zker<<<dim3(BATCH, 4), dim3(256), 0, stream>>>(inputs, mask, qparams, zws);
  scanker<<<dim3(BATCH, 4), dim3(512), 0, stream>>>(zws, mask, W, bias, out);
}